// Round 8
// baseline (180.368 us; speedup 1.0000x reference)
//
#include <hip/hip_runtime.h>
#include <hip/hip_bf16.h>

typedef __attribute__((ext_vector_type(8))) short bh8;
typedef __attribute__((ext_vector_type(4))) float fx4;
typedef __attribute__((ext_vector_type(8))) int i32x8;
typedef __attribute__((ext_vector_type(4))) int i32x4;

typedef const __attribute__((address_space(1))) unsigned int* gas_p;
typedef __attribute__((address_space(3))) unsigned int* las_p;

#define MFMA(a, b, c) __builtin_amdgcn_mfma_f32_16x16x32_bf16((a), (b), (c), 0, 0, 0)
// MX-scaled fp8 MFMA, K=128, unit scales (E8M0 127 -> 2^0): plain fp8 numerics at 2x rate
#define MFMAS(a, b, c) __builtin_amdgcn_mfma_scale_f32_16x16x128_f8f6f4( \
    (a), (b), (c), 0, 0, 0, 0x7f7f7f7f, 0, 0x7f7f7f7f)

__device__ __forceinline__ unsigned short f2bf(float f) {
  unsigned u = __builtin_bit_cast(unsigned, f);
  u += 0x7fff + ((u >> 16) & 1);   // RTNE
  return (unsigned short)(u >> 16);
}

__device__ __forceinline__ float bflo2f(unsigned u) { return __builtin_bit_cast(float, u << 16); }

__device__ __forceinline__ void gld16(const void* g, void* l) {
  __builtin_amdgcn_global_load_lds((gas_p)g, (las_p)l, 16, 0, 0);
}

// ---------------- weight transpose: w1[128,512]->w1t[512,128] bf16, w2[512,128]->w2t[128,512] bf16
__global__ __launch_bounds__(256) void transpose_weights(const float* __restrict__ w1,
                                                         const float* __restrict__ w2,
                                                         unsigned short* __restrict__ w1t,
                                                         unsigned short* __restrict__ w2t) {
  const int tgl = blockIdx.x * 256 + threadIdx.x;  // 0..65535
  { const int h = tgl >> 7, d = tgl & 127; w1t[tgl] = f2bf(w1[d * 512 + h]); }
  { const int d = tgl >> 9, h = tgl & 511; w2t[tgl] = f2bf(w2[h * 128 + d]); }
}

// ---------------- LN over D=128 + transpose to ht[b*128+d][m] (fp8 e4m3) == B^T[512][8192]
__global__ __launch_bounds__(256) void ln1_transpose(const float* __restrict__ x,
                                                     unsigned char* __restrict__ ht) {
  const int t = threadIdx.x, lane = t & 63, w = t >> 6;
  const int mt = blockIdx.x, b = blockIdx.y;
  __shared__ unsigned short tile[128 * 64];  // [d][m-chunk swizzled], bf16 staging
  const float* xb = x + ((size_t)b * 8192 + (size_t)mt * 64) * 128;
  for (int it = 0; it < 16; ++it) {
    const int r = w * 16 + it;  // local row 0..63
    const float2 v = *(const float2*)(xb + r * 128 + lane * 2);
    float s = v.x + v.y, s2 = v.x * v.x + v.y * v.y;
    #pragma unroll
    for (int o = 1; o < 64; o <<= 1) { s += __shfl_xor(s, o); s2 += __shfl_xor(s2, o); }
    const float mean = s * 0.0078125f;
    const float var = s2 * 0.0078125f - mean * mean;
    const float rstd = rsqrtf(var + 1e-5f);
    const int mc = r >> 3, ml = r & 7;
    const int d0 = lane * 2, d1 = d0 + 1;
    tile[d0 * 64 + ((mc ^ (d0 & 7)) << 3) + ml] = f2bf((v.x - mean) * rstd);
    tile[d1 * 64 + ((mc ^ (d1 & 7)) << 3) + ml] = f2bf((v.y - mean) * rstd);
  }
  __syncthreads();
  unsigned char* hb = ht + (size_t)b * 128 * 8192 + (size_t)mt * 64;
  #pragma unroll
  for (int i = 0; i < 4; ++i) {
    const int idx = i * 256 + t;
    const int d = idx >> 3, mc = idx & 7;
    const bh8 vv = *(const bh8*)(tile + d * 64 + ((mc ^ (d & 7)) << 3));
    int lo = 0, hi = 0;
    lo = __builtin_amdgcn_cvt_pk_fp8_f32(bflo2f((unsigned short)vv[0]),
                                         bflo2f((unsigned short)vv[1]), lo, false);
    lo = __builtin_amdgcn_cvt_pk_fp8_f32(bflo2f((unsigned short)vv[2]),
                                         bflo2f((unsigned short)vv[3]), lo, true);
    hi = __builtin_amdgcn_cvt_pk_fp8_f32(bflo2f((unsigned short)vv[4]),
                                         bflo2f((unsigned short)vv[5]), hi, false);
    hi = __builtin_amdgcn_cvt_pk_fp8_f32(bflo2f((unsigned short)vv[6]),
                                         bflo2f((unsigned short)vv[7]), hi, true);
    *(uint2*)(hb + (size_t)d * 8192 + mc * 8) = (uint2){(unsigned)lo, (unsigned)hi};
  }
}

// ---------------- fused exp-softmax + attn GEMM, streaming design.
// U[n,col] = sum_m exp(adj[n,m])*ht[col,m];  S[n] = sum_m exp(adj[n,m]).
// BM=64, BN=512, BK=128 (MX-fp8 K-instr), split-K z=4, grid (128,4)=512 blocks,
// 256 threads (4 waves, each owns 128 cols) -> 2 blocks/CU (8 KB LDS, <=256 VGPR).
// A = exp(adj) through 8 KB LDS (read-once); B-fragments read DIRECTLY from global
// (ht slice is 1 MB/z, L2-resident).  Only 2 barriers per K-tile, no vmcnt drains:
// adj(t+1) is issued early in tile t, in flight across the whole tile's compute.
__global__ __launch_bounds__(256, 2) void fused_attn(const float* __restrict__ adj,
                                                     const unsigned char* __restrict__ ht,
                                                     unsigned short* __restrict__ pbuf,
                                                     float* __restrict__ sden) {
  const int tid = threadIdx.x, lane = tid & 63, wn = tid >> 6;
  const int mt = blockIdx.x, z = blockIdx.y;
  const int kbase = z * 2048;

  __shared__ unsigned char Al[64 * 128];  // 8 KB, single-buffered (2 barriers/tile)

  fx4 acc[4][8];
  #pragma unroll
  for (int i = 0; i < 4; ++i)
    #pragma unroll
    for (int j = 0; j < 8; ++j) acc[i][j] = (fx4){0.f, 0.f, 0.f, 0.f};

  i32x8 afr[4];

  // A-staging: thread owns row ar = tid>>2, k-quarter aq = tid&3 (32 floats)
  const int ar = tid >> 2, aq = tid & 3;
  const float* aroot = adj + (size_t)(mt * 64 + ar) * 8192 + kbase;
  float sacc = 0.f;
  float4 a4[8];
  unsigned pk[8];

  auto issueAdj = [&](int tau) {
    #pragma unroll
    for (int j = 0; j < 8; ++j)
      a4[j] = *(const float4*)(aroot + tau * 128 + j * 16 + aq * 4);
  };
  auto expCvt = [&]() {
    #pragma unroll
    for (int j = 0; j < 8; ++j) {
      const float e0 = __expf(a4[j].x), e1 = __expf(a4[j].y);
      const float e2 = __expf(a4[j].z), e3 = __expf(a4[j].w);
      sacc += (e0 + e1) + (e2 + e3);
      int d = 0;
      d = __builtin_amdgcn_cvt_pk_fp8_f32(e0, e1, d, false);
      d = __builtin_amdgcn_cvt_pk_fp8_f32(e2, e3, d, true);
      pk[j] = (unsigned)d;
    }
  };
  auto writeA = [&]() {
    #pragma unroll
    for (int j = 0; j < 8; ++j)
      *(unsigned*)&Al[ar * 128 + ((j ^ (ar & 7)) << 4) + aq * 4] = pk[j];
  };
  auto ldAall = [&]() {
    #pragma unroll
    for (int mf = 0; mf < 4; ++mf) {
      const int rr = mf * 16 + (lane & 15);
      const int gb = (lane >> 4) * 2;
      const unsigned char* base = &Al[rr * 128];
      const i32x4 lo = *(const i32x4*)(base + ((gb ^ (rr & 7)) << 4));
      const i32x4 hi = *(const i32x4*)(base + (((gb + 1) ^ (rr & 7)) << 4));
      afr[mf] = (i32x8){lo.x, lo.y, lo.z, lo.w, hi.x, hi.y, hi.z, hi.w};
    }
  };

  // ---- prologue: tile 0 A into LDS ----
  issueAdj(0);
  expCvt();   // compiler waits vmcnt for a4
  writeA();
  asm volatile("s_waitcnt lgkmcnt(0)" ::: "memory");
  __builtin_amdgcn_sched_barrier(0);
  __builtin_amdgcn_s_barrier();
  __builtin_amdgcn_sched_barrier(0);

  // ---- 16 K-tiles, free-flowing (B from L2, compiler-scheduled) ----
  for (int tt = 0; tt < 16; ++tt) {
    ldAall();                       // compiler inserts lgkmcnt before afr use
    if (tt < 15) issueAdj(tt + 1);  // in flight across the whole tile
    asm volatile("s_waitcnt lgkmcnt(0)" ::: "memory");  // my ds_reads done (ordering)
    __builtin_amdgcn_sched_barrier(0);
    __builtin_amdgcn_s_barrier();   // all waves done reading Al -> Al free
    __builtin_amdgcn_sched_barrier(0);

    const unsigned char* bb = ht + kbase + tt * 128 + (size_t)(lane >> 4) * 32;
    #pragma unroll
    for (int p = 0; p < 8; ++p) {
      const int c = wn * 128 + p * 16 + (lane & 15);
      const unsigned char* cb = bb + (size_t)c * 8192;
      const i32x4 blo = *(const i32x4*)(cb);
      const i32x4 bhi = *(const i32x4*)(cb + 16);
      const i32x8 bfr = (i32x8){blo.x, blo.y, blo.z, blo.w, bhi.x, bhi.y, bhi.z, bhi.w};
      #pragma unroll
      for (int mf = 0; mf < 4; ++mf)
        acc[mf][p] = MFMAS(afr[mf], bfr, acc[mf][p]);
    }

    if (tt < 15) {
      expCvt();   // waits vmcnt for a4(tt+1)
      writeA();
      asm volatile("s_waitcnt lgkmcnt(0)" ::: "memory");  // writes complete
      __builtin_amdgcn_sched_barrier(0);
    }
    __builtin_amdgcn_s_barrier();   // writes visible before next ldAall
    __builtin_amdgcn_sched_barrier(0);
  }

  // ---- denominator: reduce k-quarter partials within each row-quad ----
  sacc += __shfl_xor(sacc, 1);
  sacc += __shfl_xor(sacc, 2);
  if (aq == 0) sden[(size_t)z * 8192 + mt * 64 + ar] = sacc;

  // ---- store unnormalized partial U as bf16: pbuf[z][row n][col b*128+d] ----
  unsigned short* po = pbuf + (size_t)z * 8192 * 512;
  #pragma unroll
  for (int mf = 0; mf < 4; ++mf)
    #pragma unroll
    for (int nf = 0; nf < 8; ++nf) {
      const int col = wn * 128 + nf * 16 + (lane & 15);
      #pragma unroll
      for (int q = 0; q < 4; ++q) {
        const int row = mt * 64 + mf * 16 + (lane >> 4) * 4 + q;
        po[(size_t)row * 512 + col] = f2bf(acc[mf][nf][q]);
      }
    }
}

// ---------------- fused LN2 + FFN: x1 = x + (sum_z U_z)/(sum_z S_z); h1 = LN(x1) -> As;
// out = x1 + relu(h1@w1+b1)@w2 + b2.  x1 parked f32 in As/W1c LDS after their last read.
#define SWZ16(ks, r) (((((ks) & 7) ^ ((r) & 7)) | ((ks) & 8)))
__global__ __launch_bounds__(512) void ln_ffn_kernel(const float* __restrict__ x,
                                                     const unsigned short* __restrict__ pbuf,
                                                     const float* __restrict__ sden,
                                                     const unsigned short* __restrict__ w1t,
                                                     const unsigned short* __restrict__ w2t,
                                                     const float* __restrict__ b1,
                                                     const float* __restrict__ b2,
                                                     float* __restrict__ out) {
  const int t = threadIdx.x, lane = t & 63, w = t >> 6;
  const int wr = w >> 1, wc = w & 1;   // 8 waves: 4x32 rows, 2x64 cols
  const int row0 = blockIdx.x * 128;
  __shared__ unsigned short As[128 * 128];
  __shared__ unsigned short W1c[128 * 128];
  __shared__ unsigned short W2c[128 * 128];
  __shared__ unsigned short Ts[128 * 128];

  auto stageW1 = [&](int hc) {
    #pragma unroll
    for (int i = 0; i < 4; ++i) {
      const int idx = i * 512 + t;
      const int row = idx >> 4, kc = idx & 15;
      const int kcs = (kc & 8) | ((kc & 7) ^ (row & 7));
      gld16(w1t + (size_t)(hc * 128 + row) * 128 + kcs * 8, W1c + (idx & ~63) * 8);
    }
  };
  auto stageW2 = [&](int hc) {
    #pragma unroll
    for (int i = 0; i < 4; ++i) {
      const int idx = i * 512 + t;
      const int row = idx >> 4, kc = idx & 15;
      const int kcs = (kc & 8) | ((kc & 7) ^ (row & 7));
      gld16(w2t + (size_t)row * 512 + hc * 128 + kcs * 8, W2c + (idx & ~63) * 8);
    }
  };

  stageW1(0); stageW2(0);

  // x1 = x + (sum U)/(sum S); LN over D=128 (4 threads/row); h1 -> As (bf16, swizzled)
  const int r = t >> 2, q = t & 3, c0 = q * 32;
  const int rowg = row0 + r;
  const int bb = rowg >> 13, nn = rowg & 8191;
  float xv[32];
  {
    const float den = sden[nn] + sden[8192 + nn] + sden[16384 + nn] + sden[24576 + nn];
    const float rinv = 1.f / den;
    const float* xp = x + (size_t)rowg * 128 + c0;
    #pragma unroll
    for (int j = 0; j < 8; ++j) {
      const float4 v4 = *(const float4*)(xp + 4 * j);
      xv[4 * j] = v4.x; xv[4 * j + 1] = v4.y; xv[4 * j + 2] = v4.z; xv[4 * j + 3] = v4.w;
    }
    #pragma unroll
    for (int z = 0; z < 4; ++z) {
      const unsigned short* pp = pbuf + ((size_t)z * 8192 + nn) * 512 + bb * 128 + c0;
      #pragma unroll
      for (int j = 0; j < 4; ++j) {
        const bh8 pv = *(const bh8*)(pp + 8 * j);
        #pragma unroll
        for (int e = 0; e < 8; ++e) xv[8 * j + e] += bflo2f((unsigned short)pv[e]) * rinv;
      }
    }
  }
  float s = 0.f, s2 = 0.f;
  #pragma unroll
  for (int j = 0; j < 32; ++j) { s += xv[j]; s2 += xv[j] * xv[j]; }
  s += __shfl_xor(s, 1); s2 += __shfl_xor(s2, 1);
  s += __shfl_xor(s, 2); s2 += __shfl_xor(s2, 2);
  const float mean = s * 0.0078125f;
  const float var = s2 * 0.0078125f - mean * mean;
  const float rstd = rsqrtf(var + 1e-5f);
  #pragma unroll
  for (int j = 0; j < 4; ++j) {
    const int g = q * 4 + j;
    bh8 pk;
    #pragma unroll
    for (int e = 0; e < 8; ++e) pk[e] = (short)f2bf((xv[8 * j + e] - mean) * rstd);
    *(bh8*)(As + r * 128 + SWZ16(g, r) * 8) = pk;
  }
  __syncthreads();  // As ready; W(0) staged

  fx4 accO[2][4];
  #pragma unroll
  for (int i = 0; i < 2; ++i)
    #pragma unroll
    for (int j = 0; j < 4; ++j) accO[i][j] = (fx4){0.f, 0.f, 0.f, 0.f};

  for (int hc = 0; hc < 4; ++hc) {
    if (hc > 0) stageW2(hc);  // overlaps GEMM1; drained at post-Ts barrier
    fx4 accT[2][4];
    #pragma unroll
    for (int i = 0; i < 2; ++i)
      #pragma unroll
      for (int j = 0; j < 4; ++j) accT[i][j] = (fx4){0.f, 0.f, 0.f, 0.f};
    #pragma unroll
    for (int kk = 0; kk < 4; ++kk) {
      const int ks = kk * 4 + (lane >> 4);
      bh8 af[2], bfr[4];
      #pragma unroll
      for (int f = 0; f < 2; ++f) {
        const int ra = wr * 32 + f * 16 + (lane & 15);
        af[f] = *(const bh8*)(As + ra * 128 + SWZ16(ks, ra) * 8);
      }
      #pragma unroll
      for (int f = 0; f < 4; ++f) {
        const int rb = wc * 64 + f * 16 + (lane & 15);
        bfr[f] = *(const bh8*)(W1c + rb * 128 + SWZ16(ks, rb) * 8);
      }
      #pragma unroll
      for (int fm = 0; fm < 2; ++fm)
        #pragma unroll
        for (int fn = 0; fn < 4; ++fn) accT[fm][fn] = MFMA(af[fm], bfr[fn], accT[fm][fn]);
    }
    // bias + relu -> Ts (bf16, swizzled)
    #pragma unroll
    for (int fm = 0; fm < 2; ++fm)
      #pragma unroll
      for (int fn = 0; fn < 4; ++fn) {
        const int col = wc * 64 + fn * 16 + (lane & 15);
        const float bv = b1[hc * 128 + col];
        const int c = col >> 3;
        #pragma unroll
        for (int qq = 0; qq < 4; ++qq) {
          const int row = wr * 32 + fm * 16 + (lane >> 4) * 4 + qq;
          float vv = accT[fm][fn][qq] + bv;
          vv = fmaxf(vv, 0.f);
          Ts[row * 128 + SWZ16(c, row) * 8 + (col & 7)] = f2bf(vv);
        }
      }
    __syncthreads();  // Ts ready; As/W1c GEMM1 reads done; W2c(hc) landed
    if (hc < 3) {
      stageW1(hc + 1);  // overlaps GEMM2; drained at loop-end barrier
    } else {
      // park x1 (f32) into As (rows 0-63) / W1c (rows 64-127) — both dead now
      float* dst = (r < 64) ? (float*)As + r * 128 + c0 : (float*)W1c + (r - 64) * 128 + c0;
      #pragma unroll
      for (int j = 0; j < 8; ++j)
        *(float4*)(dst + 4 * j) =
            (float4){xv[4 * j], xv[4 * j + 1], xv[4 * j + 2], xv[4 * j + 3]};
    }
    #pragma unroll
    for (int kk = 0; kk < 4; ++kk) {
      const int ks = kk * 4 + (lane >> 4);
      bh8 af[2], bfr[4];
      #pragma unroll
      for (int f = 0; f < 2; ++f) {
        const int ra = wr * 32 + f * 16 + (lane & 15);
        af[f] = *(const bh8*)(Ts + ra * 128 + SWZ16(ks, ra) * 8);
      }
      #pragma unroll
      for (int f = 0; f < 4; ++f) {
        const int rb = wc * 64 + f * 16 + (lane & 15);
        bfr[f] = *(const bh8*)(W2c + rb * 128 + SWZ16(ks, rb) * 8);
      }
      #pragma unroll
      for (int fm = 0; fm < 2; ++fm)
        #pragma unroll
        for (int fn = 0; fn < 4; ++fn) accO[fm][fn] = MFMA(af[fm], bfr[fn], accO[fm][fn]);
    }
    __syncthreads();
  }

  const float* x1a = (const float*)As;
  const float* x1b = (const float*)W1c;
  float* op = out + (size_t)row0 * 128;
  #pragma unroll
  for (int fm = 0; fm < 2; ++fm)
    #pragma unroll
    for (int fn = 0; fn < 4; ++fn) {
      const int col = wc * 64 + fn * 16 + (lane & 15);
      const float bv = b2[col];
      #pragma unroll
      for (int qq = 0; qq < 4; ++qq) {
        const int row = wr * 32 + fm * 16 + (lane >> 4) * 4 + qq;
        const float x1v = (row < 64) ? x1a[row * 128 + col] : x1b[(row - 64) * 128 + col];
        op[row * 128 + col] = x1v + accO[fm][fn][qq] + bv;
      }
    }
}

extern "C" void kernel_launch(void* const* d_in, const int* in_sizes, int n_in,
                              void* d_out, int out_size, void* d_ws, size_t ws_size,
                              hipStream_t stream) {
  const float* x   = (const float*)d_in[0];
  const float* adj = (const float*)d_in[1];
  const float* w1  = (const float*)d_in[4];
  const float* b1  = (const float*)d_in[5];
  const float* w2  = (const float*)d_in[6];
  const float* b2  = (const float*)d_in[7];
  float* out = (float*)d_out;

  char* p = (char*)d_ws;
  unsigned short* w1t  = (unsigned short*)p; p += (size_t)512 * 128 * 2;
  unsigned short* w2t  = (unsigned short*)p; p += (size_t)128 * 512 * 2;
  unsigned char*  ht   = (unsigned char*)p;  p += (size_t)4 * 128 * 8192;
  unsigned short* pbuf = (unsigned short*)p; p += (size_t)4 * 8192 * 512 * 2;
  float*          sden = (float*)p;          p += (size_t)4 * 8192 * 4;

  transpose_weights<<<256, 256, 0, stream>>>(w1, w2, w1t, w2t);
  ln1_transpose<<<dim3(128, 4), 256, 0, stream>>>(x, ht);
  fused_attn<<<dim3(128, 4), 256, 0, stream>>>(adj, ht, pbuf, sden);
  ln_ffn_kernel<<<256, 512, 0, stream>>>(x, pbuf, sden, w1t, w2t, b1, b2, out);
}

// Round 9
// 151.149 us; speedup vs baseline: 1.1933x; 1.1933x over previous
//
#include <hip/hip_runtime.h>
#include <hip/hip_bf16.h>

typedef __attribute__((ext_vector_type(8))) short bh8;
typedef __attribute__((ext_vector_type(4))) float fx4;
typedef __attribute__((ext_vector_type(8))) int i32x8;
typedef __attribute__((ext_vector_type(4))) int i32x4;

typedef const __attribute__((address_space(1))) unsigned int* gas_p;
typedef __attribute__((address_space(3))) unsigned int* las_p;

#define MFMA(a, b, c) __builtin_amdgcn_mfma_f32_16x16x32_bf16((a), (b), (c), 0, 0, 0)
// MX-scaled fp8 MFMA, K=128, unit scales (E8M0 127 -> 2^0): plain fp8 numerics at 2x rate
#define MFMAS(a, b, c) __builtin_amdgcn_mfma_scale_f32_16x16x128_f8f6f4( \
    (a), (b), (c), 0, 0, 0, 0x7f7f7f7f, 0, 0x7f7f7f7f)

__device__ __forceinline__ unsigned short f2bf(float f) {
  unsigned u = __builtin_bit_cast(unsigned, f);
  u += 0x7fff + ((u >> 16) & 1);   // RTNE
  return (unsigned short)(u >> 16);
}

__device__ __forceinline__ float bflo2f(unsigned u) { return __builtin_bit_cast(float, u << 16); }

__device__ __forceinline__ void gld16(const void* g, void* l) {
  __builtin_amdgcn_global_load_lds((gas_p)g, (las_p)l, 16, 0, 0);
}

// ---------------- weight transpose: w1[128,512]->w1t[512,128] bf16, w2[512,128]->w2t[128,512] bf16
__global__ __launch_bounds__(256) void transpose_weights(const float* __restrict__ w1,
                                                         const float* __restrict__ w2,
                                                         unsigned short* __restrict__ w1t,
                                                         unsigned short* __restrict__ w2t) {
  const int tgl = blockIdx.x * 256 + threadIdx.x;  // 0..65535
  { const int h = tgl >> 7, d = tgl & 127; w1t[tgl] = f2bf(w1[d * 512 + h]); }
  { const int d = tgl >> 9, h = tgl & 511; w2t[tgl] = f2bf(w2[h * 128 + d]); }
}

// ---------------- LN over D=128 + transpose to ht[b*128+d][m] (fp8 e4m3) == B^T[512][8192]
__global__ __launch_bounds__(256) void ln1_transpose(const float* __restrict__ x,
                                                     unsigned char* __restrict__ ht) {
  const int t = threadIdx.x, lane = t & 63, w = t >> 6;
  const int mt = blockIdx.x, b = blockIdx.y;
  __shared__ unsigned short tile[128 * 64];  // [d][m-chunk swizzled], bf16 staging
  const float* xb = x + ((size_t)b * 8192 + (size_t)mt * 64) * 128;
  for (int it = 0; it < 16; ++it) {
    const int r = w * 16 + it;  // local row 0..63
    const float2 v = *(const float2*)(xb + r * 128 + lane * 2);
    float s = v.x + v.y, s2 = v.x * v.x + v.y * v.y;
    #pragma unroll
    for (int o = 1; o < 64; o <<= 1) { s += __shfl_xor(s, o); s2 += __shfl_xor(s2, o); }
    const float mean = s * 0.0078125f;
    const float var = s2 * 0.0078125f - mean * mean;
    const float rstd = rsqrtf(var + 1e-5f);
    const int mc = r >> 3, ml = r & 7;
    const int d0 = lane * 2, d1 = d0 + 1;
    tile[d0 * 64 + ((mc ^ (d0 & 7)) << 3) + ml] = f2bf((v.x - mean) * rstd);
    tile[d1 * 64 + ((mc ^ (d1 & 7)) << 3) + ml] = f2bf((v.y - mean) * rstd);
  }
  __syncthreads();
  unsigned char* hb = ht + (size_t)b * 128 * 8192 + (size_t)mt * 64;
  #pragma unroll
  for (int i = 0; i < 4; ++i) {
    const int idx = i * 256 + t;
    const int d = idx >> 3, mc = idx & 7;
    const bh8 vv = *(const bh8*)(tile + d * 64 + ((mc ^ (d & 7)) << 3));
    int lo = 0, hi = 0;
    lo = __builtin_amdgcn_cvt_pk_fp8_f32(bflo2f((unsigned short)vv[0]),
                                         bflo2f((unsigned short)vv[1]), lo, false);
    lo = __builtin_amdgcn_cvt_pk_fp8_f32(bflo2f((unsigned short)vv[2]),
                                         bflo2f((unsigned short)vv[3]), lo, true);
    hi = __builtin_amdgcn_cvt_pk_fp8_f32(bflo2f((unsigned short)vv[4]),
                                         bflo2f((unsigned short)vv[5]), hi, false);
    hi = __builtin_amdgcn_cvt_pk_fp8_f32(bflo2f((unsigned short)vv[6]),
                                         bflo2f((unsigned short)vv[7]), hi, true);
    *(uint2*)(hb + (size_t)d * 8192 + mc * 8) = (uint2){(unsigned)lo, (unsigned)hi};
  }
}

// ---------------- fused exp-softmax + attn GEMM, streaming, STAGED B.
// U[n,col] = sum_m exp(adj[n,m])*ht[col,m];  S[n] = sum_m exp(adj[n,m]).
// BM=64, BN=512, BK=128 (MX-fp8), split-K z=4, grid (128,4)=512 blocks -> 2 blocks/CU
// (LDS 8+64=72 KB).  256 threads = 4 waves, each owns 128 cols.  Per K-tile:
//   { ldA frags, issue adj(t+1), MFMA loop reading Bl }  barrier
//   { stageB(t+1) 16x gld16 (coalesced), expCvt (counted vmcnt leaves gld16 in flight),
//     writeA }  vmcnt(0)+barrier.
// adj(t+1) gets a full MFMA phase of latency cover; gld16 covers vs L2-hot ht.
__global__ __launch_bounds__(256, 2) void fused_attn(const float* __restrict__ adj,
                                                     const unsigned char* __restrict__ ht,
                                                     unsigned short* __restrict__ pbuf,
                                                     float* __restrict__ sden) {
  const int tid = threadIdx.x, lane = tid & 63, wn = tid >> 6;
  const int mt = blockIdx.x, z = blockIdx.y;
  const int kbase = z * 2048;

  __shared__ unsigned char Al[64 * 128];    // 8 KB, single-buffered
  __shared__ unsigned char Bl[512 * 128];   // 64 KB, single-buffered

  fx4 acc[4][8];
  #pragma unroll
  for (int i = 0; i < 4; ++i)
    #pragma unroll
    for (int j = 0; j < 8; ++j) acc[i][j] = (fx4){0.f, 0.f, 0.f, 0.f};

  i32x8 afr[4];

  // A-staging: thread owns row ar = tid>>2, k-quarter aq = tid&3 (32 floats = 2 granule-pairs)
  const int ar = tid >> 2, aq = tid & 3;
  const float* aroot = adj + (size_t)(mt * 64 + ar) * 8192 + kbase;
  float sacc = 0.f;
  float4 a4[8];
  unsigned pk[8];

  auto issueAdj = [&](int tau) {
    #pragma unroll
    for (int j = 0; j < 8; ++j)
      a4[j] = *(const float4*)(aroot + tau * 128 + aq * 32 + j * 4);
  };
  auto expCvt = [&]() {
    #pragma unroll
    for (int j = 0; j < 8; ++j) {
      const float e0 = __expf(a4[j].x), e1 = __expf(a4[j].y);
      const float e2 = __expf(a4[j].z), e3 = __expf(a4[j].w);
      sacc += (e0 + e1) + (e2 + e3);
      int d = 0;
      d = __builtin_amdgcn_cvt_pk_fp8_f32(e0, e1, d, false);
      d = __builtin_amdgcn_cvt_pk_fp8_f32(e2, e3, d, true);
      pk[j] = (unsigned)d;
    }
  };
  auto writeA = [&]() {
    // thread holds logical granules 2aq, 2aq+1 of row ar; phys = g ^ (ar&7)
    const i32x4 w0 = (i32x4){(int)pk[0], (int)pk[1], (int)pk[2], (int)pk[3]};
    const i32x4 w1 = (i32x4){(int)pk[4], (int)pk[5], (int)pk[6], (int)pk[7]};
    *(i32x4*)&Al[ar * 128 + (((aq * 2) ^ (ar & 7)) << 4)] = w0;
    *(i32x4*)&Al[ar * 128 + (((aq * 2 + 1) ^ (ar & 7)) << 4)] = w1;
  };
  auto stageB = [&](int tau) {
    #pragma unroll
    for (int j = 0; j < 16; ++j) {
      const int idx = j * 256 + tid;
      const int col = idx >> 3, g = idx & 7;
      gld16(ht + (size_t)col * 8192 + kbase + tau * 128 + ((g ^ (col & 7)) << 4),
            Bl + idx * 16);
    }
  };
  auto ldAall = [&]() {
    #pragma unroll
    for (int mf = 0; mf < 4; ++mf) {
      const int rr = mf * 16 + (lane & 15);
      const int gb = (lane >> 4) * 2;
      const unsigned char* base = &Al[rr * 128];
      const i32x4 lo = *(const i32x4*)(base + ((gb ^ (rr & 7)) << 4));
      const i32x4 hi = *(const i32x4*)(base + (((gb + 1) ^ (rr & 7)) << 4));
      afr[mf] = (i32x8){lo.x, lo.y, lo.z, lo.w, hi.x, hi.y, hi.z, hi.w};
    }
  };

  // ---- prologue: tile 0 ----
  issueAdj(0);
  expCvt();        // compiler waits vmcnt for a4
  writeA();
  stageB(0);       // 16 gld16
  asm volatile("s_waitcnt lgkmcnt(0) vmcnt(0)" ::: "memory");
  __builtin_amdgcn_sched_barrier(0);
  __builtin_amdgcn_s_barrier();
  __builtin_amdgcn_sched_barrier(0);

  // ---- 16 K-tiles ----
  for (int tt = 0; tt < 16; ++tt) {
    ldAall();
    if (tt < 15) issueAdj(tt + 1);   // oldest vmem: full MFMA phase of cover

    #pragma unroll
    for (int nf = 0; nf < 8; ++nf) {
      const int c = wn * 128 + nf * 16 + (lane & 15);
      const int gb = (lane >> 4) * 2;
      const unsigned char* cb = &Bl[c * 128];
      const i32x4 blo = *(const i32x4*)(cb + ((gb ^ (c & 7)) << 4));
      const i32x4 bhi = *(const i32x4*)(cb + (((gb + 1) ^ (c & 7)) << 4));
      const i32x8 bfr = (i32x8){blo.x, blo.y, blo.z, blo.w, bhi.x, bhi.y, bhi.z, bhi.w};
      #pragma unroll
      for (int mf = 0; mf < 4; ++mf)
        acc[mf][nf] = MFMAS(afr[mf], bfr, acc[mf][nf]);
    }

    asm volatile("s_waitcnt lgkmcnt(0)" ::: "memory");  // my Al/Bl reads done
    __builtin_amdgcn_sched_barrier(0);
    __builtin_amdgcn_s_barrier();    // all waves done reading -> LDS free
    __builtin_amdgcn_sched_barrier(0);

    if (tt < 15) {
      stageB(tt + 1);   // issue gld16 early; exp VALU covers L2 latency
      expCvt();         // counted vmcnt: waits adj only, gld16 stays in flight
      writeA();
      asm volatile("s_waitcnt lgkmcnt(0) vmcnt(0)" ::: "memory");
      __builtin_amdgcn_sched_barrier(0);
      __builtin_amdgcn_s_barrier();  // A+B for tile tt+1 visible
      __builtin_amdgcn_sched_barrier(0);
    }
  }

  // ---- denominator: reduce k-quarter partials within each row-quad ----
  sacc += __shfl_xor(sacc, 1);
  sacc += __shfl_xor(sacc, 2);
  if (aq == 0) sden[(size_t)z * 8192 + mt * 64 + ar] = sacc;

  // ---- store unnormalized partial U as bf16: pbuf[z][row n][col b*128+d] ----
  unsigned short* po = pbuf + (size_t)z * 8192 * 512;
  #pragma unroll
  for (int mf = 0; mf < 4; ++mf)
    #pragma unroll
    for (int nf = 0; nf < 8; ++nf) {
      const int col = wn * 128 + nf * 16 + (lane & 15);
      #pragma unroll
      for (int q = 0; q < 4; ++q) {
        const int row = mt * 64 + mf * 16 + (lane >> 4) * 4 + q;
        po[(size_t)row * 512 + col] = f2bf(acc[mf][nf][q]);
      }
    }
}

// ---------------- fused LN2 + FFN: x1 = x + (sum_z U_z)/(sum_z S_z); h1 = LN(x1) -> As;
// out = x1 + relu(h1@w1+b1)@w2 + b2.  x1 parked f32 in As/W1c LDS after their last read.
#define SWZ16(ks, r) (((((ks) & 7) ^ ((r) & 7)) | ((ks) & 8)))
__global__ __launch_bounds__(512) void ln_ffn_kernel(const float* __restrict__ x,
                                                     const unsigned short* __restrict__ pbuf,
                                                     const float* __restrict__ sden,
                                                     const unsigned short* __restrict__ w1t,
                                                     const unsigned short* __restrict__ w2t,
                                                     const float* __restrict__ b1,
                                                     const float* __restrict__ b2,
                                                     float* __restrict__ out) {
  const int t = threadIdx.x, lane = t & 63, w = t >> 6;
  const int wr = w >> 1, wc = w & 1;   // 8 waves: 4x32 rows, 2x64 cols
  const int row0 = blockIdx.x * 128;
  __shared__ unsigned short As[128 * 128];
  __shared__ unsigned short W1c[128 * 128];
  __shared__ unsigned short W2c[128 * 128];
  __shared__ unsigned short Ts[128 * 128];

  auto stageW1 = [&](int hc) {
    #pragma unroll
    for (int i = 0; i < 4; ++i) {
      const int idx = i * 512 + t;
      const int row = idx >> 4, kc = idx & 15;
      const int kcs = (kc & 8) | ((kc & 7) ^ (row & 7));
      gld16(w1t + (size_t)(hc * 128 + row) * 128 + kcs * 8, W1c + (idx & ~63) * 8);
    }
  };
  auto stageW2 = [&](int hc) {
    #pragma unroll
    for (int i = 0; i < 4; ++i) {
      const int idx = i * 512 + t;
      const int row = idx >> 4, kc = idx & 15;
      const int kcs = (kc & 8) | ((kc & 7) ^ (row & 7));
      gld16(w2t + (size_t)row * 512 + hc * 128 + kcs * 8, W2c + (idx & ~63) * 8);
    }
  };

  stageW1(0); stageW2(0);

  // x1 = x + (sum U)/(sum S); LN over D=128 (4 threads/row); h1 -> As (bf16, swizzled)
  const int r = t >> 2, q = t & 3, c0 = q * 32;
  const int rowg = row0 + r;
  const int bb = rowg >> 13, nn = rowg & 8191;
  float xv[32];
  {
    const float den = sden[nn] + sden[8192 + nn] + sden[16384 + nn] + sden[24576 + nn];
    const float rinv = 1.f / den;
    const float* xp = x + (size_t)rowg * 128 + c0;
    #pragma unroll
    for (int j = 0; j < 8; ++j) {
      const float4 v4 = *(const float4*)(xp + 4 * j);
      xv[4 * j] = v4.x; xv[4 * j + 1] = v4.y; xv[4 * j + 2] = v4.z; xv[4 * j + 3] = v4.w;
    }
    #pragma unroll
    for (int z = 0; z < 4; ++z) {
      const unsigned short* pp = pbuf + ((size_t)z * 8192 + nn) * 512 + bb * 128 + c0;
      #pragma unroll
      for (int j = 0; j < 4; ++j) {
        const bh8 pv = *(const bh8*)(pp + 8 * j);
        #pragma unroll
        for (int e = 0; e < 8; ++e) xv[8 * j + e] += bflo2f((unsigned short)pv[e]) * rinv;
      }
    }
  }
  float s = 0.f, s2 = 0.f;
  #pragma unroll
  for (int j = 0; j < 32; ++j) { s += xv[j]; s2 += xv[j] * xv[j]; }
  s += __shfl_xor(s, 1); s2 += __shfl_xor(s2, 1);
  s += __shfl_xor(s, 2); s2 += __shfl_xor(s2, 2);
  const float mean = s * 0.0078125f;
  const float var = s2 * 0.0078125f - mean * mean;
  const float rstd = rsqrtf(var + 1e-5f);
  #pragma unroll
  for (int j = 0; j < 4; ++j) {
    const int g = q * 4 + j;
    bh8 pk;
    #pragma unroll
    for (int e = 0; e < 8; ++e) pk[e] = (short)f2bf((xv[8 * j + e] - mean) * rstd);
    *(bh8*)(As + r * 128 + SWZ16(g, r) * 8) = pk;
  }
  __syncthreads();  // As ready; W(0) staged

  fx4 accO[2][4];
  #pragma unroll
  for (int i = 0; i < 2; ++i)
    #pragma unroll
    for (int j = 0; j < 4; ++j) accO[i][j] = (fx4){0.f, 0.f, 0.f, 0.f};

  for (int hc = 0; hc < 4; ++hc) {
    if (hc > 0) stageW2(hc);  // overlaps GEMM1; drained at post-Ts barrier
    fx4 accT[2][4];
    #pragma unroll
    for (int i = 0; i < 2; ++i)
      #pragma unroll
      for (int j = 0; j < 4; ++j) accT[i][j] = (fx4){0.f, 0.f, 0.f, 0.f};
    #pragma unroll
    for (int kk = 0; kk < 4; ++kk) {
      const int ks = kk * 4 + (lane >> 4);
      bh8 af[2], bfr[4];
      #pragma unroll
      for (int f = 0; f < 2; ++f) {
        const int ra = wr * 32 + f * 16 + (lane & 15);
        af[f] = *(const bh8*)(As + ra * 128 + SWZ16(ks, ra) * 8);
      }
      #pragma unroll
      for (int f = 0; f < 4; ++f) {
        const int rb = wc * 64 + f * 16 + (lane & 15);
        bfr[f] = *(const bh8*)(W1c + rb * 128 + SWZ16(ks, rb) * 8);
      }
      #pragma unroll
      for (int fm = 0; fm < 2; ++fm)
        #pragma unroll
        for (int fn = 0; fn < 4; ++fn) accT[fm][fn] = MFMA(af[fm], bfr[fn], accT[fm][fn]);
    }
    // bias + relu -> Ts (bf16, swizzled)
    #pragma unroll
    for (int fm = 0; fm < 2; ++fm)
      #pragma unroll
      for (int fn = 0; fn < 4; ++fn) {
        const int col = wc * 64 + fn * 16 + (lane & 15);
        const float bv = b1[hc * 128 + col];
        const int c = col >> 3;
        #pragma unroll
        for (int qq = 0; qq < 4; ++qq) {
          const int row = wr * 32 + fm * 16 + (lane >> 4) * 4 + qq;
          float vv = accT[fm][fn][qq] + bv;
          vv = fmaxf(vv, 0.f);
          Ts[row * 128 + SWZ16(c, row) * 8 + (col & 7)] = f2bf(vv);
        }
      }
    __syncthreads();  // Ts ready; As/W1c GEMM1 reads done; W2c(hc) landed
    if (hc < 3) {
      stageW1(hc + 1);  // overlaps GEMM2; drained at loop-end barrier
    } else {
      // park x1 (f32) into As (rows 0-63) / W1c (rows 64-127) — both dead now
      float* dst = (r < 64) ? (float*)As + r * 128 + c0 : (float*)W1c + (r - 64) * 128 + c0;
      #pragma unroll
      for (int j = 0; j < 8; ++j)
        *(float4*)(dst + 4 * j) =
            (float4){xv[4 * j], xv[4 * j + 1], xv[4 * j + 2], xv[4 * j + 3]};
    }
    #pragma unroll
    for (int kk = 0; kk < 4; ++kk) {
      const int ks = kk * 4 + (lane >> 4);
      bh8 af[2], bfr[4];
      #pragma unroll
      for (int f = 0; f < 2; ++f) {
        const int ra = wr * 32 + f * 16 + (lane & 15);
        af[f] = *(const bh8*)(Ts + ra * 128 + SWZ16(ks, ra) * 8);
      }
      #pragma unroll
      for (int f = 0; f < 4; ++f) {
        const int rb = wc * 64 + f * 16 + (lane & 15);
        bfr[f] = *(const bh8*)(W2c + rb * 128 + SWZ16(ks, rb) * 8);
      }
      #pragma unroll
      for (int fm = 0; fm < 2; ++fm)
        #pragma unroll
        for (int fn = 0; fn < 4; ++fn) accO[fm][fn] = MFMA(af[fm], bfr[fn], accO[fm][fn]);
    }
    __syncthreads();
  }

  const float* x1a = (const float*)As;
  const float* x1b = (const float*)W1c;
  float* op = out + (size_t)row0 * 128;
  #pragma unroll
  for (int fm = 0; fm < 2; ++fm)
    #pragma unroll
    for (int fn = 0; fn < 4; ++fn) {
      const int col = wc * 64 + fn * 16 + (lane & 15);
      const float bv = b2[col];
      #pragma unroll
      for (int qq = 0; qq < 4; ++qq) {
        const int row = wr * 32 + fm * 16 + (lane >> 4) * 4 + qq;
        const float x1v = (row < 64) ? x1a[row * 128 + col] : x1b[(row - 64) * 128 + col];
        op[row * 128 + col] = x1v + accO[fm][fn][qq] + bv;
      }
    }
}

extern "C" void kernel_launch(void* const* d_in, const int* in_sizes, int n_in,
                              void* d_out, int out_size, void* d_ws, size_t ws_size,
                              hipStream_t stream) {
  const float* x   = (const float*)d_in[0];
  const float* adj = (const float*)d_in[1];
  const float* w1  = (const float*)d_in[4];
  const float* b1  = (const float*)d_in[5];
  const float* w2  = (const float*)d_in[6];
  const float* b2  = (const float*)d_in[7];
  float* out = (float*)d_out;

  char* p = (char*)d_ws;
  unsigned short* w1t  = (unsigned short*)p; p += (size_t)512 * 128 * 2;
  unsigned short* w2t  = (unsigned short*)p; p += (size_t)128 * 512 * 2;
  unsigned char*  ht   = (unsigned char*)p;  p += (size_t)4 * 128 * 8192;
  unsigned short* pbuf = (unsigned short*)p; p += (size_t)4 * 8192 * 512 * 2;
  float*          sden = (float*)p;          p += (size_t)4 * 8192 * 4;

  transpose_weights<<<256, 256, 0, stream>>>(w1, w2, w1t, w2t);
  ln1_transpose<<<dim3(128, 4), 256, 0, stream>>>(x, ht);
  fused_attn<<<dim3(128, 4), 256, 0, stream>>>(adj, ht, pbuf, sden);
  ln_ffn_kernel<<<256, 512, 0, stream>>>(x, pbuf, sden, w1t, w2t, b1, b2, out);
}